// Round 8
// baseline (640.721 us; speedup 1.0000x reference)
//
#include <hip/hip_runtime.h>
#include <hip/hip_bf16.h>

#define N_NODES 50000
#define N_EDGES 800000
#define D_IN 64
#define D_EDGE 32
#define D_HID 128
#define TILES_TOTAL (N_EDGES / 16)

using u32 = unsigned int;
typedef short bf16x8 __attribute__((ext_vector_type(8)));
typedef float f32x4 __attribute__((ext_vector_type(4)));

// ---- bf16 helpers via bit ops (RNE) ----
__device__ __forceinline__ u32 f2bf(float f) {
    u32 b = __float_as_uint(f);
    return (b + 0x7FFFu + ((b >> 16) & 1u)) >> 16;
}
__device__ __forceinline__ u32 pk2(float lo, float hi) {
    return f2bf(lo) | (f2bf(hi) << 16);
}
__device__ __forceinline__ float bf2f(u32 us) { return __uint_as_float(us << 16); }
__device__ __forceinline__ float tanh_fast(float x) {
    float e = __expf(2.f * x);                       // +inf -> 1, 0 -> -1, NaN-free
    return 1.f - 2.f * __builtin_amdgcn_rcpf(e + 1.f);
}
__device__ __forceinline__ bf16x8 as_frag(uint4 v) { return __builtin_bit_cast(bf16x8, v); }

// ============ one-time weight fragment pack (hidden-unit relabeling) ============
__global__ void pack_kernel(const float* __restrict__ W1, const float* __restrict__ W2,
                            uint4* __restrict__ w1p, uint4* __restrict__ w2p) {
    int gid = blockIdx.x * 256 + threadIdx.x;
    if (gid >= 24 * 64) return;
    int frag = gid >> 6, lane = gid & 63;
    int q = (lane >> 4) & 3, c = lane & 15;
    u32 p[4];
    if (frag < 8) {
        int t = frag;
#pragma unroll
        for (int j01 = 0; j01 < 4; ++j01) {
            float lo = W1[(q * 8 + 2 * j01) * D_HID + t * 16 + c];
            float hi = W1[(q * 8 + 2 * j01 + 1) * D_HID + t * 16 + c];
            p[j01] = pk2(lo, hi);
        }
        w1p[t * 64 + lane] = make_uint4(p[0], p[1], p[2], p[3]);
    } else {
        int f = frag - 8, s = f >> 2, t2 = f & 3;
#pragma unroll
        for (int j01 = 0; j01 < 4; ++j01) {
            int j0 = 2 * j01, j1 = j0 + 1;
            int u0 = 32 * s + 16 * (j0 >> 2) + 4 * q + (j0 & 3);
            int u1 = 32 * s + 16 * (j1 >> 2) + 4 * q + (j1 & 3);
            p[j01] = pk2(W2[u0 * D_IN + t2 * 16 + c], W2[u1 * D_IN + t2 * 16 + c]);
        }
        w2p[f * 64 + lane] = make_uint4(p[0], p[1], p[2], p[3]);
    }
}

// ============ edge MLP: src-sorted compute, tgt-rank full-line stores ============
__global__ __launch_bounds__(256, 6) void edge_mfma_kernel(
    const float* __restrict__ x,
    const int* __restrict__ srcs /* [E] src node at src-rank p */,
    const int* __restrict__ perm /* [E] edge id at src-rank p */,
    const int* __restrict__ tr   /* [E] tgt-rank of edge at src-rank p */,
    const float* __restrict__ ea,
    const float* __restrict__ b1, const float* __restrict__ b2,
    const float* __restrict__ av,
    const uint4* __restrict__ w1p, const uint4* __restrict__ w2p,
    u32* __restrict__ msg_t /* [E][32] u32, TGT-rank order */,
    float* __restrict__ scores_t /* [E], TGT-rank order */)
{
    __shared__ uint4 w2lds[1024];                      // 16 KB
    __shared__ u32 stage[4][512];                      // 2 KB per wave (wave-private)
    int tid = threadIdx.x;
#pragma unroll
    for (int ph = 0; ph < 4; ++ph) w2lds[tid + ph * 256] = w2p[tid + ph * 256];
    __syncthreads();                                   // one-time

    const int wid = tid >> 6, lane = tid & 63, q = lane >> 4, c = lane & 15;

    bf16x8 w1f[8];
#pragma unroll
    for (int t = 0; t < 8; ++t) w1f[t] = as_frag(w1p[t * 64 + lane]);
    f32x4 b2f[4], avf[4];
#pragma unroll
    for (int t2 = 0; t2 < 4; ++t2) {
        float4 tb = *(const float4*)(b2 + t2 * 16 + q * 4);
        float4 ta = *(const float4*)(av + t2 * 16 + q * 4);
        b2f[t2] = f32x4{tb.x, tb.y, tb.z, tb.w};
        avf[t2] = f32x4{ta.x, ta.y, ta.z, ta.w};
    }

    const int nw = gridDim.x * 4;
    const int rc = lane >> 2;                          // read-back row
    const int swr = (rc & 7) << 2;

    for (int T = blockIdx.x * 4 + wid; T < TILES_TOTAL; T += nw) {
        const int pb = T * 16;
        const int e = perm[pb + c];
        const int sidx = srcs[pb + c];
        const int trc = tr[pb + c];                    // tgt-rank of this lane's edge
        const int trm = tr[pb + rc];                   // tgt-rank of read-back row

        const float4* ar = (const float4*)(ea + (size_t)e * D_EDGE + q * 8);
        float4 va = ar[0], vb = ar[1];
        bf16x8 a1 = as_frag(make_uint4(pk2(va.x, va.y), pk2(va.z, va.w),
                                       pk2(vb.x, vb.y), pk2(vb.z, vb.w)));

        bf16x8 bfrag[4];
#pragma unroll
        for (int h2 = 0; h2 < 2; ++h2) {
            f32x4 acc[4];
#pragma unroll
            for (int tt = 0; tt < 4; ++tt) {
                int t = h2 * 4 + tt;
                float4 bb = *(const float4*)(b1 + t * 16 + q * 4);
                f32x4 ci = f32x4{bb.x, bb.y, bb.z, bb.w};
                acc[tt] = __builtin_amdgcn_mfma_f32_16x16x32_bf16(w1f[t], a1, ci, 0, 0, 0);
            }
#pragma unroll
            for (int tt = 0; tt < 4; ++tt)
#pragma unroll
                for (int r = 0; r < 4; ++r) acc[tt][r] = tanh_fast(acc[tt][r]);
            bfrag[h2 * 2 + 0] = as_frag(make_uint4(
                pk2(acc[0][0], acc[0][1]), pk2(acc[0][2], acc[0][3]),
                pk2(acc[1][0], acc[1][1]), pk2(acc[1][2], acc[1][3])));
            bfrag[h2 * 2 + 1] = as_frag(make_uint4(
                pk2(acc[2][0], acc[2][1]), pk2(acc[2][2], acc[2][3]),
                pk2(acc[3][0], acc[3][1]), pk2(acc[3][2], acc[3][3])));
        }

        f32x4 acc2[4];
#pragma unroll
        for (int t2 = 0; t2 < 4; ++t2) acc2[t2] = b2f[t2];
#pragma unroll
        for (int s = 0; s < 4; ++s)
#pragma unroll
            for (int t2 = 0; t2 < 4; ++t2) {
                bf16x8 wf = as_frag(w2lds[(s * 4 + t2) * 64 + lane]);
                acc2[t2] = __builtin_amdgcn_mfma_f32_16x16x32_bf16(wf, bfrag[s], acc2[t2], 0, 0, 0);
            }

        // messages + score partials (x gather is src-clustered => coalesced)
        float pr = 0.f;
#pragma unroll
        for (int t2 = 0; t2 < 4; ++t2) {
            float4 xv = *(const float4*)(x + (size_t)sidx * D_IN + t2 * 16 + q * 4);
            acc2[t2][0] *= xv.x; acc2[t2][1] *= xv.y;
            acc2[t2][2] *= xv.z; acc2[t2][3] *= xv.w;
            pr = fmaf(acc2[t2][0], avf[t2][0], pr);
            pr = fmaf(acc2[t2][1], avf[t2][1], pr);
            pr = fmaf(acc2[t2][2], avf[t2][2], pr);
            pr = fmaf(acc2[t2][3], avf[t2][3], pr);
        }
        pr += __shfl_xor(pr, 16);
        pr += __shfl_xor(pr, 32);

        // stage (wave-private, XOR-swizzled: word w at position w^((c&7)<<2))
        u32* st = stage[wid] + c * 32;
#pragma unroll
        for (int t2 = 0; t2 < 4; ++t2) {
            int sw = (t2 * 8 + q * 2) ^ ((c & 7) << 2);
            uint2 pk; pk.x = pk2(acc2[t2][0], acc2[t2][1]);
            pk.y = pk2(acc2[t2][2], acc2[t2][3]);
            *(uint2*)(st + sw) = pk;
        }
        // read back (same wave, swizzle is an involution) and store full 128B rows
        uint4 v0 = *(uint4*)(stage[wid] + rc * 32 + (((lane & 3) * 8 + 0) ^ swr));
        uint4 v1 = *(uint4*)(stage[wid] + rc * 32 + (((lane & 3) * 8 + 4) ^ swr));
        u32* gdst = msg_t + (size_t)trm * 32 + (lane & 3) * 8;
        *(uint4*)(gdst + 0) = v0;
        *(uint4*)(gdst + 4) = v1;
        if (lane < 16) scores_t[trc] = pr;
    }
}

// ============ sort chain ============
__global__ void zero_kernel(int* __restrict__ p, int n) {
    int i = blockIdx.x * 256 + threadIdx.x;
    if (i < n) p[i] = 0;
}

__global__ void hist2_kernel(const int* __restrict__ src, const int* __restrict__ tgt,
                             int* __restrict__ cnt /* [2N]: s then t */) {
    int e = blockIdx.x * 256 + threadIdx.x;
    if (e < N_EDGES) {
        atomicAdd(&cnt[src[e]], 1);
        atomicAdd(&cnt[N_NODES + tgt[e]], 1);
    }
}

__device__ __forceinline__ int block_incl_scan(int v, int lane, int wid, int* ws, int nwaves) {
    int incl = v;
#pragma unroll
    for (int off = 1; off < 64; off <<= 1) {
        int t = __shfl_up(incl, off);
        if (lane >= off) incl += t;
    }
    if (lane == 63) ws[wid] = incl;
    __syncthreads();
    if (threadIdx.x == 0) {
        int s = 0;
        for (int w = 0; w < nwaves; ++w) { int x = ws[w]; ws[w] = s; s += x; }
    }
    __syncthreads();
    return incl + ws[wid];
}

// combined scan over 2N counts -> offsC[2N+1]
__global__ __launch_bounds__(256) void scanA_kernel(const int* __restrict__ cnt,
                                                    int* __restrict__ offsC,
                                                    int* __restrict__ csum) {
    __shared__ int ws[4];
    int tid = threadIdx.x, lane = tid & 63, wid = tid >> 6;
    int i = blockIdx.x * 256 + tid;
    int v = (i < 2 * N_NODES) ? cnt[i] : 0;
    int incl = block_incl_scan(v, lane, wid, ws, 4);
    if (i < 2 * N_NODES) offsC[i + 1] = incl;
    if (tid == 255) csum[blockIdx.x] = incl;
}

__global__ __launch_bounds__(512) void scanB_kernel(int* __restrict__ csum,
                                                    int* __restrict__ offsC, int nchunks) {
    __shared__ int ws[8];
    int tid = threadIdx.x, lane = tid & 63, wid = tid >> 6;
    int v = (tid < nchunks) ? csum[tid] : 0;
    int incl = block_incl_scan(v, lane, wid, ws, 8);
    if (tid < nchunks) csum[tid] = incl - v;   // exclusive base per chunk
    if (tid == 0) offsC[0] = 0;
}

__global__ void scanC_kernel(int* __restrict__ offsC, const int* __restrict__ csum) {
    int i = blockIdx.x * 256 + threadIdx.x;
    if (i < 2 * N_NODES) offsC[i + 1] += csum[i >> 8];
}

// fused scatter: computes src-rank AND tgt-rank per edge in one pass
__global__ void scatter_kernel(const int* __restrict__ src, const int* __restrict__ tgt,
                               const int* __restrict__ offsC,
                               int* __restrict__ cur /* [2N]: s then t */,
                               int* __restrict__ perm, int* __restrict__ srcs,
                               int* __restrict__ tr, int* __restrict__ sorted) {
    int e = blockIdx.x * 256 + threadIdx.x;
    if (e >= N_EDGES) return;
    int s = src[e], t = tgt[e];
    int ps = offsC[s] + atomicAdd(&cur[s], 1);
    int pt = (offsC[N_NODES + t] - N_EDGES) + atomicAdd(&cur[N_NODES + t], 1);
    perm[ps] = e;
    srcs[ps] = s;
    tr[ps] = pt;
    sorted[pt] = e;
}

// ============ per-node softmax + aggregation (fully streaming reads) ============
__global__ __launch_bounds__(256) void agg_kernel(
    const int* __restrict__ offsC, const int* __restrict__ sorted,
    const float* __restrict__ ss /* tgt-rank order */,
    const u32* __restrict__ msg32 /* tgt-rank order */,
    float* __restrict__ out, float* __restrict__ aw_out)
{
    int node = blockIdx.x * 4 + (threadIdx.x >> 6);
    int lane = threadIdx.x & 63;
    int beg = offsC[N_NODES + node] - N_EDGES;
    int end = offsC[N_NODES + node + 1] - N_EDGES;

    float mx = -3.4e38f;
    for (int k = beg + lane; k < end; k += 64) mx = fmaxf(mx, ss[k]);
#pragma unroll
    for (int off = 32; off; off >>= 1) mx = fmaxf(mx, __shfl_xor(mx, off));

    float den = 0.f;
    for (int k = beg + lane; k < end; k += 64) den += __expf(ss[k] - mx);
#pragma unroll
    for (int off = 32; off; off >>= 1) den += __shfl_xor(den, off);
    float rden = 1.f / den;

    int p4 = lane >> 4, ch = lane & 15;
    float a0 = 0.f, a1 = 0.f, a2 = 0.f, a3 = 0.f;
    for (int kb = beg; kb < end; kb += 4) {
        int k = kb + p4;
        if (k < end) {
            float aw = __expf(ss[k] - mx) * rden;
            uint2 m = *(const uint2*)(msg32 + (size_t)k * 32 + ch * 2);
            a0 = fmaf(bf2f(m.x & 0xffffu), aw, a0);
            a1 = fmaf(bf2f(m.x >> 16), aw, a1);
            a2 = fmaf(bf2f(m.y & 0xffffu), aw, a2);
            a3 = fmaf(bf2f(m.y >> 16), aw, a3);
            if (ch == 0) aw_out[sorted[k]] = aw;
        }
    }
    a0 += __shfl_xor(a0, 16); a0 += __shfl_xor(a0, 32);
    a1 += __shfl_xor(a1, 16); a1 += __shfl_xor(a1, 32);
    a2 += __shfl_xor(a2, 16); a2 += __shfl_xor(a2, 32);
    a3 += __shfl_xor(a3, 16); a3 += __shfl_xor(a3, 32);
    if (lane < 16) {
        float4 o; o.x = a0; o.y = a1; o.z = a2; o.w = a3;
        *(float4*)(out + (size_t)node * 64 + ch * 4) = o;
    }
}

// ============ launch ============
extern "C" void kernel_launch(void* const* d_in, const int* in_sizes, int n_in,
                              void* d_out, int out_size, void* d_ws, size_t ws_size,
                              hipStream_t stream)
{
    const float* x  = (const float*)d_in[0];
    const int*   ei = (const int*)d_in[1];
    const float* ea = (const float*)d_in[2];
    const float* W1 = (const float*)d_in[3];
    const float* b1 = (const float*)d_in[4];
    const float* W2 = (const float*)d_in[5];
    const float* b2 = (const float*)d_in[6];
    const float* av = (const float*)d_in[7];
    const int* src = ei;
    const int* tgt = ei + N_EDGES;

    char* ws = (char*)d_ws;
    size_t off = 0;
    u32* msg_t     = (u32*)(ws + off);   off += (size_t)N_EDGES * 32 * 4;  // 102.4 MB
    uint4* w1p     = (uint4*)(ws + off); off += 8 * 64 * 16;
    uint4* w2p     = (uint4*)(ws + off); off += 16 * 64 * 16;
    float* scores_t= (float*)(ws + off); off += (size_t)N_EDGES * 4;
    int* sorted    = (int*)(ws + off);   off += (size_t)N_EDGES * 4;
    int* perm      = (int*)(ws + off);   off += (size_t)N_EDGES * 4;
    int* srcs      = (int*)(ws + off);   off += (size_t)N_EDGES * 4;
    int* tr        = (int*)(ws + off);   off += (size_t)N_EDGES * 4;
    int* cnt       = (int*)(ws + off);   off += (size_t)2 * N_NODES * 4;  // hist s||t
    int* cur       = (int*)(ws + off);   off += (size_t)2 * N_NODES * 4;  // cursors s||t
    int* offsC     = (int*)(ws + off);   off += (size_t)(2 * N_NODES + 1) * 4;
    int* csum      = (int*)(ws + off);   off += 512 * 4;

    float* out    = (float*)d_out;
    float* aw_out = out + (size_t)N_NODES * 64;

    const int NCH2 = (2 * N_NODES + 255) / 256;   // 391

    pack_kernel<<<6, 256, 0, stream>>>(W1, W2, w1p, w2p);
    zero_kernel<<<(4 * N_NODES + 255) / 256, 256, 0, stream>>>(cnt, 4 * N_NODES);
    hist2_kernel<<<(N_EDGES + 255) / 256, 256, 0, stream>>>(src, tgt, cnt);
    scanA_kernel<<<NCH2, 256, 0, stream>>>(cnt, offsC, csum);
    scanB_kernel<<<1, 512, 0, stream>>>(csum, offsC, NCH2);
    scanC_kernel<<<NCH2, 256, 0, stream>>>(offsC, csum);
    scatter_kernel<<<(N_EDGES + 255) / 256, 256, 0, stream>>>(src, tgt, offsC, cur,
                                                              perm, srcs, tr, sorted);
    edge_mfma_kernel<<<1536, 256, 0, stream>>>(x, srcs, perm, tr, ea, b1, b2, av,
                                               w1p, w2p, msg_t, scores_t);
    agg_kernel<<<(N_NODES + 3) / 4, 256, 0, stream>>>(offsC, sorted,
                                                      scores_t, msg_t, out, aw_out);
}

// Round 9
// 523.273 us; speedup vs baseline: 1.2245x; 1.2245x over previous
//
#include <hip/hip_runtime.h>
#include <hip/hip_bf16.h>

#define N_NODES 50000
#define N_EDGES 800000
#define D_IN 64
#define D_EDGE 32
#define D_HID 128
#define TILES_TOTAL (N_EDGES / 16)

using u32 = unsigned int;
typedef short bf16x8 __attribute__((ext_vector_type(8)));
typedef float f32x4 __attribute__((ext_vector_type(4)));

// ---- bf16 helpers via bit ops (RNE) ----
__device__ __forceinline__ u32 f2bf(float f) {
    u32 b = __float_as_uint(f);
    return (b + 0x7FFFu + ((b >> 16) & 1u)) >> 16;
}
__device__ __forceinline__ u32 pk2(float lo, float hi) {
    return f2bf(lo) | (f2bf(hi) << 16);
}
__device__ __forceinline__ float bf2f(u32 us) { return __uint_as_float(us << 16); }
__device__ __forceinline__ float tanh_fast(float x) {
    float e = __expf(2.f * x);                       // +inf -> 1, 0 -> -1, NaN-free
    return 1.f - 2.f * __builtin_amdgcn_rcpf(e + 1.f);
}
__device__ __forceinline__ bf16x8 as_frag(uint4 v) { return __builtin_bit_cast(bf16x8, v); }

// ============ one-time weight fragment pack (hidden-unit relabeling) ============
__global__ void pack_kernel(const float* __restrict__ W1, const float* __restrict__ W2,
                            uint4* __restrict__ w1p, uint4* __restrict__ w2p) {
    int gid = blockIdx.x * 256 + threadIdx.x;
    if (gid >= 24 * 64) return;
    int frag = gid >> 6, lane = gid & 63;
    int q = (lane >> 4) & 3, c = lane & 15;
    u32 p[4];
    if (frag < 8) {
        int t = frag;
#pragma unroll
        for (int j01 = 0; j01 < 4; ++j01) {
            float lo = W1[(q * 8 + 2 * j01) * D_HID + t * 16 + c];
            float hi = W1[(q * 8 + 2 * j01 + 1) * D_HID + t * 16 + c];
            p[j01] = pk2(lo, hi);
        }
        w1p[t * 64 + lane] = make_uint4(p[0], p[1], p[2], p[3]);
    } else {
        int f = frag - 8, s = f >> 2, t2 = f & 3;
#pragma unroll
        for (int j01 = 0; j01 < 4; ++j01) {
            int j0 = 2 * j01, j1 = j0 + 1;
            int u0 = 32 * s + 16 * (j0 >> 2) + 4 * q + (j0 & 3);
            int u1 = 32 * s + 16 * (j1 >> 2) + 4 * q + (j1 & 3);
            p[j01] = pk2(W2[u0 * D_IN + t2 * 16 + c], W2[u1 * D_IN + t2 * 16 + c]);
        }
        w2p[f * 64 + lane] = make_uint4(p[0], p[1], p[2], p[3]);
    }
}

// ============ edge MLP: src-sorted compute, tgt-rank FULL-LINE stores ============
__global__ __launch_bounds__(256, 4) void edge_mfma_kernel(
    const float* __restrict__ x,
    const int* __restrict__ srcs /* [E] src node at src-rank p */,
    const int* __restrict__ perm /* [E] edge id at src-rank p */,
    const int* __restrict__ tr   /* [E] tgt-rank of edge at src-rank p */,
    const float* __restrict__ ea,
    const float* __restrict__ b1, const float* __restrict__ b2,
    const float* __restrict__ av,
    const uint4* __restrict__ w1p, const uint4* __restrict__ w2p,
    u32* __restrict__ msg_t /* [E][32] u32, TGT-rank order */,
    float* __restrict__ scores_t /* [E], TGT-rank order */)
{
    __shared__ uint4 w2lds[1024];                      // 16 KB
    __shared__ uint4 w1lds[512];                       // 8 KB
    __shared__ u32 stage[4][512];                      // 8 KB total (wave-private)
    int tid = threadIdx.x;
#pragma unroll
    for (int ph = 0; ph < 4; ++ph) w2lds[tid + ph * 256] = w2p[tid + ph * 256];
#pragma unroll
    for (int ph = 0; ph < 2; ++ph) w1lds[tid + ph * 256] = w1p[tid + ph * 256];
    __syncthreads();                                   // one-time

    const int wid = tid >> 6, lane = tid & 63, q = lane >> 4, c = lane & 15;
    const int r0 = lane >> 3, ch = lane & 7;           // readback: row chunk ids

    f32x4 b2f[4], avf[4];
#pragma unroll
    for (int t2 = 0; t2 < 4; ++t2) {
        float4 tb = *(const float4*)(b2 + t2 * 16 + q * 4);
        float4 ta = *(const float4*)(av + t2 * 16 + q * 4);
        b2f[t2] = f32x4{tb.x, tb.y, tb.z, tb.w};
        avf[t2] = f32x4{ta.x, ta.y, ta.z, ta.w};
    }

    const int nw = gridDim.x * 4;

    for (int T = blockIdx.x * 4 + wid; T < TILES_TOTAL; T += nw) {
        const int pb = T * 16;
        const int e = perm[pb + c];
        const int sidx = srcs[pb + c];
        const int trc = tr[pb + c];                    // tgt-rank of this lane's edge

        const float4* ar = (const float4*)(ea + (size_t)e * D_EDGE + q * 8);
        float4 va = ar[0], vb = ar[1];
        bf16x8 a1 = as_frag(make_uint4(pk2(va.x, va.y), pk2(va.z, va.w),
                                       pk2(vb.x, vb.y), pk2(vb.z, vb.w)));

        bf16x8 bfrag[4];
#pragma unroll
        for (int h2 = 0; h2 < 2; ++h2) {
            f32x4 acc[4];
#pragma unroll
            for (int tt = 0; tt < 4; ++tt) {
                int t = h2 * 4 + tt;
                float4 bb = *(const float4*)(b1 + t * 16 + q * 4);
                f32x4 ci = f32x4{bb.x, bb.y, bb.z, bb.w};
                bf16x8 wf1 = as_frag(w1lds[t * 64 + lane]);
                acc[tt] = __builtin_amdgcn_mfma_f32_16x16x32_bf16(wf1, a1, ci, 0, 0, 0);
            }
#pragma unroll
            for (int tt = 0; tt < 4; ++tt)
#pragma unroll
                for (int r = 0; r < 4; ++r) acc[tt][r] = tanh_fast(acc[tt][r]);
            bfrag[h2 * 2 + 0] = as_frag(make_uint4(
                pk2(acc[0][0], acc[0][1]), pk2(acc[0][2], acc[0][3]),
                pk2(acc[1][0], acc[1][1]), pk2(acc[1][2], acc[1][3])));
            bfrag[h2 * 2 + 1] = as_frag(make_uint4(
                pk2(acc[2][0], acc[2][1]), pk2(acc[2][2], acc[2][3]),
                pk2(acc[3][0], acc[3][1]), pk2(acc[3][2], acc[3][3])));
        }

        f32x4 acc2[4];
#pragma unroll
        for (int t2 = 0; t2 < 4; ++t2) acc2[t2] = b2f[t2];
#pragma unroll
        for (int s = 0; s < 4; ++s)
#pragma unroll
            for (int t2 = 0; t2 < 4; ++t2) {
                bf16x8 wf = as_frag(w2lds[(s * 4 + t2) * 64 + lane]);
                acc2[t2] = __builtin_amdgcn_mfma_f32_16x16x32_bf16(wf, bfrag[s], acc2[t2], 0, 0, 0);
            }

        // messages + score partials (x gather is src-clustered => coalesced)
        float pr = 0.f;
#pragma unroll
        for (int t2 = 0; t2 < 4; ++t2) {
            float4 xv = *(const float4*)(x + (size_t)sidx * D_IN + t2 * 16 + q * 4);
            acc2[t2][0] *= xv.x; acc2[t2][1] *= xv.y;
            acc2[t2][2] *= xv.z; acc2[t2][3] *= xv.w;
            pr = fmaf(acc2[t2][0], avf[t2][0], pr);
            pr = fmaf(acc2[t2][1], avf[t2][1], pr);
            pr = fmaf(acc2[t2][2], avf[t2][2], pr);
            pr = fmaf(acc2[t2][3], avf[t2][3], pr);
        }
        pr += __shfl_xor(pr, 16);
        pr += __shfl_xor(pr, 32);

        // stage (wave-private, XOR-swizzled: word w of row c at w^((c&7)<<2))
        u32* st = stage[wid] + c * 32;
#pragma unroll
        for (int t2 = 0; t2 < 4; ++t2) {
            int sw = (t2 * 8 + q * 2) ^ ((c & 7) << 2);
            uint2 pk; pk.x = pk2(acc2[t2][0], acc2[t2][1]);
            pk.y = pk2(acc2[t2][2], acc2[t2][3]);
            *(uint2*)(st + sw) = pk;
        }
        // readback: 8 consecutive lanes fully cover one 128-B row -> no RMW
#pragma unroll
        for (int i = 0; i < 2; ++i) {
            int r = i * 8 + r0;
            int trm = tr[pb + r];
            uint4 v = *(uint4*)(stage[wid] + r * 32 + ((ch * 4) ^ ((r & 7) << 2)));
            *(uint4*)(msg_t + (size_t)trm * 32 + ch * 4) = v;
        }
        if (lane < 16) scores_t[trc] = pr;
    }
}

// ============ sort chain ============
__global__ void zero_kernel(int* __restrict__ p, int n) {
    int i = blockIdx.x * 256 + threadIdx.x;
    if (i < n) p[i] = 0;
}

__global__ void hist2_kernel(const int* __restrict__ src, const int* __restrict__ tgt,
                             int* __restrict__ cnt /* [2N]: s then t */) {
    int e = blockIdx.x * 256 + threadIdx.x;
    if (e < N_EDGES) {
        atomicAdd(&cnt[src[e]], 1);
        atomicAdd(&cnt[N_NODES + tgt[e]], 1);
    }
}

__device__ __forceinline__ int block_incl_scan(int v, int lane, int wid, int* ws, int nwaves) {
    int incl = v;
#pragma unroll
    for (int off = 1; off < 64; off <<= 1) {
        int t = __shfl_up(incl, off);
        if (lane >= off) incl += t;
    }
    if (lane == 63) ws[wid] = incl;
    __syncthreads();
    if (threadIdx.x == 0) {
        int s = 0;
        for (int w = 0; w < nwaves; ++w) { int x = ws[w]; ws[w] = s; s += x; }
    }
    __syncthreads();
    return incl + ws[wid];
}

// combined scan over 2N counts -> offsC[2N+1]
__global__ __launch_bounds__(256) void scanA_kernel(const int* __restrict__ cnt,
                                                    int* __restrict__ offsC,
                                                    int* __restrict__ csum) {
    __shared__ int ws[4];
    int tid = threadIdx.x, lane = tid & 63, wid = tid >> 6;
    int i = blockIdx.x * 256 + tid;
    int v = (i < 2 * N_NODES) ? cnt[i] : 0;
    int incl = block_incl_scan(v, lane, wid, ws, 4);
    if (i < 2 * N_NODES) offsC[i + 1] = incl;
    if (tid == 255) csum[blockIdx.x] = incl;
}

__global__ __launch_bounds__(512) void scanB_kernel(int* __restrict__ csum,
                                                    int* __restrict__ offsC, int nchunks) {
    __shared__ int ws[8];
    int tid = threadIdx.x, lane = tid & 63, wid = tid >> 6;
    int v = (tid < nchunks) ? csum[tid] : 0;
    int incl = block_incl_scan(v, lane, wid, ws, 8);
    if (tid < nchunks) csum[tid] = incl - v;   // exclusive base per chunk
    if (tid == 0) offsC[0] = 0;
}

__global__ void scanC_kernel(int* __restrict__ offsC, const int* __restrict__ csum) {
    int i = blockIdx.x * 256 + threadIdx.x;
    if (i < 2 * N_NODES) offsC[i + 1] += csum[i >> 8];
}

// fused scatter: computes src-rank AND tgt-rank per edge in one pass
__global__ void scatter_kernel(const int* __restrict__ src, const int* __restrict__ tgt,
                               const int* __restrict__ offsC,
                               int* __restrict__ cur /* [2N]: s then t */,
                               int* __restrict__ perm, int* __restrict__ srcs,
                               int* __restrict__ tr, int* __restrict__ sorted) {
    int e = blockIdx.x * 256 + threadIdx.x;
    if (e >= N_EDGES) return;
    int s = src[e], t = tgt[e];
    int ps = offsC[s] + atomicAdd(&cur[s], 1);
    int pt = (offsC[N_NODES + t] - N_EDGES) + atomicAdd(&cur[N_NODES + t], 1);
    perm[ps] = e;
    srcs[ps] = s;
    tr[ps] = pt;
    sorted[pt] = e;
}

// ============ per-node softmax + aggregation (fully streaming reads) ============
__global__ __launch_bounds__(256) void agg_kernel(
    const int* __restrict__ offsC, const int* __restrict__ sorted,
    const float* __restrict__ ss /* tgt-rank order */,
    const u32* __restrict__ msg32 /* tgt-rank order */,
    float* __restrict__ out, float* __restrict__ aw_out)
{
    int node = blockIdx.x * 4 + (threadIdx.x >> 6);
    int lane = threadIdx.x & 63;
    int beg = offsC[N_NODES + node] - N_EDGES;
    int end = offsC[N_NODES + node + 1] - N_EDGES;

    float mx = -3.4e38f;
    for (int k = beg + lane; k < end; k += 64) mx = fmaxf(mx, ss[k]);
#pragma unroll
    for (int off = 32; off; off >>= 1) mx = fmaxf(mx, __shfl_xor(mx, off));

    float den = 0.f;
    for (int k = beg + lane; k < end; k += 64) den += __expf(ss[k] - mx);
#pragma unroll
    for (int off = 32; off; off >>= 1) den += __shfl_xor(den, off);
    float rden = 1.f / den;

    int p4 = lane >> 4, ch = lane & 15;
    float a0 = 0.f, a1 = 0.f, a2 = 0.f, a3 = 0.f;
    for (int kb = beg; kb < end; kb += 4) {
        int k = kb + p4;
        if (k < end) {
            float aw = __expf(ss[k] - mx) * rden;
            uint2 m = *(const uint2*)(msg32 + (size_t)k * 32 + ch * 2);
            a0 = fmaf(bf2f(m.x & 0xffffu), aw, a0);
            a1 = fmaf(bf2f(m.x >> 16), aw, a1);
            a2 = fmaf(bf2f(m.y & 0xffffu), aw, a2);
            a3 = fmaf(bf2f(m.y >> 16), aw, a3);
            if (ch == 0) aw_out[sorted[k]] = aw;
        }
    }
    a0 += __shfl_xor(a0, 16); a0 += __shfl_xor(a0, 32);
    a1 += __shfl_xor(a1, 16); a1 += __shfl_xor(a1, 32);
    a2 += __shfl_xor(a2, 16); a2 += __shfl_xor(a2, 32);
    a3 += __shfl_xor(a3, 16); a3 += __shfl_xor(a3, 32);
    if (lane < 16) {
        float4 o; o.x = a0; o.y = a1; o.z = a2; o.w = a3;
        *(float4*)(out + (size_t)node * 64 + ch * 4) = o;
    }
}

// ============ launch ============
extern "C" void kernel_launch(void* const* d_in, const int* in_sizes, int n_in,
                              void* d_out, int out_size, void* d_ws, size_t ws_size,
                              hipStream_t stream)
{
    const float* x  = (const float*)d_in[0];
    const int*   ei = (const int*)d_in[1];
    const float* ea = (const float*)d_in[2];
    const float* W1 = (const float*)d_in[3];
    const float* b1 = (const float*)d_in[4];
    const float* W2 = (const float*)d_in[5];
    const float* b2 = (const float*)d_in[6];
    const float* av = (const float*)d_in[7];
    const int* src = ei;
    const int* tgt = ei + N_EDGES;

    char* ws = (char*)d_ws;
    size_t off = 0;
    u32* msg_t     = (u32*)(ws + off);   off += (size_t)N_EDGES * 32 * 4;  // 102.4 MB
    uint4* w1p     = (uint4*)(ws + off); off += 8 * 64 * 16;
    uint4* w2p     = (uint4*)(ws + off); off += 16 * 64 * 16;
    float* scores_t= (float*)(ws + off); off += (size_t)N_EDGES * 4;
    int* sorted    = (int*)(ws + off);   off += (size_t)N_EDGES * 4;
    int* perm      = (int*)(ws + off);   off += (size_t)N_EDGES * 4;
    int* srcs      = (int*)(ws + off);   off += (size_t)N_EDGES * 4;
    int* tr        = (int*)(ws + off);   off += (size_t)N_EDGES * 4;
    int* cnt       = (int*)(ws + off);   off += (size_t)2 * N_NODES * 4;  // hist s||t
    int* cur       = (int*)(ws + off);   off += (size_t)2 * N_NODES * 4;  // cursors s||t
    int* offsC     = (int*)(ws + off);   off += (size_t)(2 * N_NODES + 1) * 4;
    int* csum      = (int*)(ws + off);   off += 512 * 4;

    float* out    = (float*)d_out;
    float* aw_out = out + (size_t)N_NODES * 64;

    const int NCH2 = (2 * N_NODES + 255) / 256;   // 391

    pack_kernel<<<6, 256, 0, stream>>>(W1, W2, w1p, w2p);
    zero_kernel<<<(4 * N_NODES + 255) / 256, 256, 0, stream>>>(cnt, 4 * N_NODES);
    hist2_kernel<<<(N_EDGES + 255) / 256, 256, 0, stream>>>(src, tgt, cnt);
    scanA_kernel<<<NCH2, 256, 0, stream>>>(cnt, offsC, csum);
    scanB_kernel<<<1, 512, 0, stream>>>(csum, offsC, NCH2);
    scanC_kernel<<<NCH2, 256, 0, stream>>>(offsC, csum);
    scatter_kernel<<<(N_EDGES + 255) / 256, 256, 0, stream>>>(src, tgt, offsC, cur,
                                                              perm, srcs, tr, sorted);
    edge_mfma_kernel<<<2048, 256, 0, stream>>>(x, srcs, perm, tr, ea, b1, b2, av,
                                               w1p, w2p, msg_t, scores_t);
    agg_kernel<<<(N_NODES + 3) / 4, 256, 0, stream>>>(offsC, sorted,
                                                      scores_t, msg_t, out, aw_out);
}